// Round 6
// baseline (6608.328 us; speedup 1.0000x reference)
//
#include <hip/hip_runtime.h>
#include <cstdint>
#include <cstddef>

#define T_SEQ 2048
#define BATCH 16
#define DIM   512
#define HID   512
#define NCOL  2048            // 4H per direction
#define XROW  520             // 512 + 8 pad (bf16 elems)

typedef __attribute__((ext_vector_type(8))) short          s8v;
typedef __attribute__((ext_vector_type(4))) float          f4v;
typedef __attribute__((ext_vector_type(4))) unsigned short h4v;

#define HXBASE(d, s) (((size_t)((d) * 2 + (s)) * BATCH) * HID)

__device__ __forceinline__ unsigned short f2b(float f) {
  unsigned u = __builtin_bit_cast(unsigned, f);
  return (unsigned short)((u + 0x7fffu + ((u >> 16) & 1u)) >> 16);  // RNE
}

// grid = 64 wgs x 256 thr. wg w: dir = w>>5, j-block = (w&31)*16.
// Wave wv's 16 B-cols packed as {gate g, j = j0+4*wv+q}, c = 4g+q, so the
// 4 gates of one (b,j) sit in lanes {q,q+4,q+8,q+12}: a 2-round shfl_xor
// 4x4 transpose replaces the LDS gate exchange. Split-K: x.Wi (K=512) is
// computed in the previous step's tail (overlapping the h poll); only
// h.Wh (K=512) is on the critical path. h exchange: epoch-tagged bf16 in
// d_ws, ping-pong slots, relaxed agent-scope ld/st, no barriers.
__global__ __launch_bounds__(256, 1)
void lstm_persist(const float* __restrict__ x, const int* __restrict__ lengths,
                  const float* __restrict__ Wi_f, const float* __restrict__ Wh_f,
                  const float* __restrict__ b_f,
                  const float* __restrict__ Wi_b, const float* __restrict__ Wh_b,
                  const float* __restrict__ b_b,
                  unsigned int* __restrict__ hx,
                  float* __restrict__ out) {
  __shared__ unsigned short Ax[2][BATCH][XROW];   // x(t) bf16, double-buffered
  __shared__ unsigned short Ah[BATCH][XROW];      // h(t-1) bf16

  const int w    = (int)blockIdx.x;
  const int dir  = w >> 5;
  const int j0   = (w & 31) * 16;
  const int tid  = (int)threadIdx.x;
  const int lane = tid & 63;
  const int wv   = tid >> 6;

  // staging/poll mapping: one (b, sub) per thread
  const int b    = tid >> 4;
  const int sub  = tid & 15;
  const int len  = lengths[b];

  // gate-math mapping (post-transpose): one (bm, jm) per thread
  const int bm   = 4 * (lane >> 4) + ((lane >> 2) & 3);
  const int jm   = j0 + 4 * wv + (lane & 3);
  const int lenm = lengths[bm];

  const float* bias = dir ? b_b : b_f;
  const float bi = bias[0 * HID + jm];
  const float bf = bias[1 * HID + jm];
  const float bg = bias[2 * HID + jm];
  const float bo = bias[3 * HID + jm];

  // ---- persistent W fragments; fragment col c=lane&15 -> global col
  //      ((c>>2)*HID + j0 + 4*wv + (c&3)) ----
  s8v wfi[16], wfh[16];
  {
    const float* Wi = dir ? Wi_b : Wi_f;
    const float* Wh = dir ? Wh_b : Wh_f;
    const int colW = ((lane >> 2) & 3) * HID + j0 + 4 * wv + (lane & 3);
    const int kb   = (lane >> 4) * 8;
#pragma unroll
    for (int kc = 0; kc < 16; ++kc) {
      const float* src = Wi + (size_t)(kc * 32 + kb) * NCOL + colW;
      s8v f;
#pragma unroll
      for (int j = 0; j < 8; ++j) f[j] = (short)f2b(src[(size_t)j * NCOL]);
      wfi[kc] = f;
    }
#pragma unroll
    for (int kc = 0; kc < 16; ++kc) {
      const float* src = Wh + (size_t)(kc * 32 + kb) * NCOL + colW;
      s8v f;
#pragma unroll
      for (int j = 0; j < 8; ++j) f[j] = (short)f2b(src[(size_t)j * NCOL]);
      wfh[kc] = f;
    }
  }

  const int arow = lane & 15;
  const int koff = (lane >> 4) * 8;

  // stage tau for step s (per staging batch b)
  auto taus = [&](int s) { return dir ? ((T_SEQ - 1 - s + len) & (T_SEQ - 1)) : s; };

  // ---- prologue: stage x(tau(0)) -> Ax[0], x(tau(1)) -> Ax[1] ----
#pragma unroll
  for (int bb = 0; bb < 2; ++bb) {
    const float* xrow = x + ((size_t)b * T_SEQ + taus(bb)) * DIM;
#pragma unroll
    for (int r = 0; r < 8; ++r) {
      const int k = sub * 4 + r * 64;
      f4v v = *(const f4v*)(xrow + k);
      h4v p; p[0] = f2b(v[0]); p[1] = f2b(v[1]); p[2] = f2b(v[2]); p[3] = f2b(v[3]);
      *(h4v*)&Ax[bb][b][k] = p;
    }
  }
  __syncthreads();

  // acc_x for t=0
  f4v accx;
  {
    f4v d0 = {0,0,0,0}, d1 = {0,0,0,0}, d2 = {0,0,0,0}, d3 = {0,0,0,0};
    const unsigned short* ap = &Ax[0][arow][koff];
#pragma unroll
    for (int kc = 0; kc < 16; kc += 4) {
      d0 = __builtin_amdgcn_mfma_f32_16x16x32_bf16(*(const s8v*)(ap + (kc+0)*32), wfi[kc+0], d0, 0,0,0);
      d1 = __builtin_amdgcn_mfma_f32_16x16x32_bf16(*(const s8v*)(ap + (kc+1)*32), wfi[kc+1], d1, 0,0,0);
      d2 = __builtin_amdgcn_mfma_f32_16x16x32_bf16(*(const s8v*)(ap + (kc+2)*32), wfi[kc+2], d2, 0,0,0);
      d3 = __builtin_amdgcn_mfma_f32_16x16x32_bf16(*(const s8v*)(ap + (kc+3)*32), wfi[kc+3], d3, 0,0,0);
    }
    accx = (d0 + d1) + (d2 + d3);
  }

  float c_state = 0.f;

  for (int t = 0; t < T_SEQ; ++t) {
    const unsigned e = (unsigned)(t + 1);
    const bool notlast = (t + 1 < T_SEQ);

    // ---- issue x(tau(t+2)) global loads early (hide under h-MFMA+gates) ----
    f4v xv[8];
    if (notlast) {
      const int tsn = (t + 2 < T_SEQ) ? (t + 2) : 0;   // clamp; garbage never read
      const float* xrow = x + ((size_t)b * T_SEQ + taus(tsn)) * DIM;
#pragma unroll
      for (int r = 0; r < 8; ++r) xv[r] = *(const f4v*)(xrow + sub * 4 + r * 64);
    }

    // ---- h-part MFMA (K=512), seeded with accx ----
    f4v acc = accx;
    if (t > 0) {
      f4v c1 = {0,0,0,0}, c2 = {0,0,0,0}, c3 = {0,0,0,0};
      const unsigned short* ap = &Ah[arow][koff];
#pragma unroll
      for (int kc = 0; kc < 16; kc += 4) {
        acc = __builtin_amdgcn_mfma_f32_16x16x32_bf16(*(const s8v*)(ap + (kc+0)*32), wfh[kc+0], acc, 0,0,0);
        c1  = __builtin_amdgcn_mfma_f32_16x16x32_bf16(*(const s8v*)(ap + (kc+1)*32), wfh[kc+1], c1,  0,0,0);
        c2  = __builtin_amdgcn_mfma_f32_16x16x32_bf16(*(const s8v*)(ap + (kc+2)*32), wfh[kc+2], c2,  0,0,0);
        c3  = __builtin_amdgcn_mfma_f32_16x16x32_bf16(*(const s8v*)(ap + (kc+3)*32), wfh[kc+3], c3,  0,0,0);
      }
      acc = (acc + c1) + (c2 + c3);
    }

    // ---- 4x4 in-wave transpose: lanes {q,q+4,q+8,q+12} gate->batch swap ----
    {
      const int gb0 = (lane >> 2) & 1;
      float t0 = __shfl_xor(gb0 ? acc[0] : acc[1], 4);
      float t1 = __shfl_xor(gb0 ? acc[2] : acc[3], 4);
      if (gb0) { acc[0] = t0; acc[2] = t1; } else { acc[1] = t0; acc[3] = t1; }
      const int gb1 = (lane >> 3) & 1;
      float u0 = __shfl_xor(gb1 ? acc[0] : acc[2], 8);
      float u1 = __shfl_xor(gb1 ? acc[1] : acc[3], 8);
      if (gb1) { acc[0] = u0; acc[1] = u1; } else { acc[2] = u0; acc[3] = u1; }
      // acc[g] = gate g for (bm, jm)
    }

    // ---- gate math (one (bm, jm) per thread); publish h, store out ----
    {
      const float gi = acc[0] + bi;
      const float gf = acc[1] + bf;
      const float gg = acc[2] + bg;
      const float go = acc[3] + bo;
      const float si = 1.f / (1.f + __expf(-gi));
      const float sf = 1.f / (1.f + __expf(-gf));
      const float so = 1.f / (1.f + __expf(-go));
      const float tg = 1.f - 2.f / (1.f + __expf(2.f * gg));
      c_state = sf * c_state + si * tg;
      const float tc = 1.f - 2.f / (1.f + __expf(2.f * c_state));
      const float h = so * tc;
      if (notlast) {
        const unsigned tagged = ((unsigned)f2b(h) << 16) | e;
        __hip_atomic_store(&hx[HXBASE(dir, e & 1) + (size_t)bm * HID + jm], tagged,
                           __ATOMIC_RELAXED, __HIP_MEMORY_SCOPE_AGENT);
      }
      const int tauo = dir ? ((T_SEQ - 1 - t + lenm) & (T_SEQ - 1)) : t;
      out[((size_t)bm * T_SEQ + tauo) * (2 * HID) + (size_t)dir * HID + jm] = h;
    }

    if (!notlast) break;

    __syncthreads();   // SYNC-A: Ah reads done everywhere; Ax[(t+1)&1] ready

    // ---- issue poll loads for h(t) (epoch e) first ----
    const unsigned* hrow = hx + HXBASE(dir, e & 1) + (size_t)b * HID;
    unsigned long long hu[16];
#pragma unroll
    for (int r = 0; r < 8; ++r) {
      const int k = sub * 4 + r * 64;
      hu[2*r]   = __hip_atomic_load((const unsigned long long*)(hrow + k),
                                    __ATOMIC_RELAXED, __HIP_MEMORY_SCOPE_AGENT);
      hu[2*r+1] = __hip_atomic_load((const unsigned long long*)(hrow + k) + 1,
                                    __ATOMIC_RELAXED, __HIP_MEMORY_SCOPE_AGENT);
    }

    // ---- x-part MFMA for step t+1 (overlaps poll latency) ----
    {
      f4v d0 = {0,0,0,0}, d1 = {0,0,0,0}, d2 = {0,0,0,0}, d3 = {0,0,0,0};
      const unsigned short* ap = &Ax[(t + 1) & 1][arow][koff];
#pragma unroll
      for (int kc = 0; kc < 16; kc += 4) {
        d0 = __builtin_amdgcn_mfma_f32_16x16x32_bf16(*(const s8v*)(ap + (kc+0)*32), wfi[kc+0], d0, 0,0,0);
        d1 = __builtin_amdgcn_mfma_f32_16x16x32_bf16(*(const s8v*)(ap + (kc+1)*32), wfi[kc+1], d1, 0,0,0);
        d2 = __builtin_amdgcn_mfma_f32_16x16x32_bf16(*(const s8v*)(ap + (kc+2)*32), wfi[kc+2], d2, 0,0,0);
        d3 = __builtin_amdgcn_mfma_f32_16x16x32_bf16(*(const s8v*)(ap + (kc+3)*32), wfi[kc+3], d3, 0,0,0);
      }
      accx = (d0 + d1) + (d2 + d3);
    }

    // ---- stage x(tau(t+2)) -> Ax[t&1] (overlaps poll latency) ----
#pragma unroll
    for (int r = 0; r < 8; ++r) {
      const int k = sub * 4 + r * 64;
      h4v p; p[0] = f2b(xv[r][0]); p[1] = f2b(xv[r][1]);
             p[2] = f2b(xv[r][2]); p[3] = f2b(xv[r][3]);
      *(h4v*)&Ax[t & 1][b][k] = p;
    }

    // ---- check tags; retry until h(t) complete ----
    {
      const unsigned long long msk = 0x0000FFFF0000FFFFULL;
      const unsigned long long pat = ((unsigned long long)e << 32) | e;
      while (true) {
        bool ok = true;
#pragma unroll
        for (int r = 0; r < 16; ++r) ok &= ((hu[r] & msk) == pat);
        if (ok) break;
        __builtin_amdgcn_s_sleep(1);
#pragma unroll
        for (int r = 0; r < 8; ++r) {
          const int k = sub * 4 + r * 64;
          hu[2*r]   = __hip_atomic_load((const unsigned long long*)(hrow + k),
                                        __ATOMIC_RELAXED, __HIP_MEMORY_SCOPE_AGENT);
          hu[2*r+1] = __hip_atomic_load((const unsigned long long*)(hrow + k) + 1,
                                        __ATOMIC_RELAXED, __HIP_MEMORY_SCOPE_AGENT);
        }
      }
    }

    // ---- stage h(t) -> Ah ----
#pragma unroll
    for (int r = 0; r < 8; ++r) {
      const int k = sub * 4 + r * 64;
      h4v p;
      p[0] = (unsigned short)(hu[2*r]   >> 16);
      p[1] = (unsigned short)(hu[2*r]   >> 48);
      p[2] = (unsigned short)(hu[2*r+1] >> 16);
      p[3] = (unsigned short)(hu[2*r+1] >> 48);
      *(h4v*)&Ah[b][k] = p;
    }
    __syncthreads();   // SYNC-B: Ah + Ax[t&1] staged for next iteration
  }
}

extern "C" void kernel_launch(void* const* d_in, const int* in_sizes, int n_in,
                              void* d_out, int out_size, void* d_ws, size_t ws_size,
                              hipStream_t stream) {
  const float* x    = (const float*)d_in[0];
  const int*   len  = (const int*)d_in[1];
  const float* Wi_f = (const float*)d_in[2];
  const float* Wh_f = (const float*)d_in[3];
  const float* b_f  = (const float*)d_in[4];
  const float* Wi_b = (const float*)d_in[5];
  const float* Wh_b = (const float*)d_in[6];
  const float* b_b  = (const float*)d_in[7];
  float* out = (float*)d_out;
  unsigned int* hx = (unsigned int*)d_ws;   // [2][2][16][512] u32 = 256 KB

  hipMemsetAsync(d_ws, 0, (size_t)2 * 2 * BATCH * HID * 4, stream);
  hipLaunchKernelGGL(lstm_persist, dim3(64), dim3(256), 0, stream,
                     x, len, Wi_f, Wh_f, b_f, Wi_b, Wh_b, b_b, hx, out);
}